// Round 1
// baseline (1656.999 us; speedup 1.0000x reference)
//
#include <hip/hip_runtime.h>
#include <math.h>

// ---------------- constants ----------------
#define T99   99
#define CC    256
#define NHH   8
#define FEAT  400
#define NS_   32
#define LSTEP 33
#define GRP   3

typedef __attribute__((ext_vector_type(8))) short s8v;   // 8 x bf16 (as raw u16)
typedef __attribute__((ext_vector_type(4))) float f4v;   // MFMA accumulator

__device__ __forceinline__ void mfma_bf16(f4v& d, s8v a, s8v b) {
  asm volatile("v_mfma_f32_16x16x32_bf16 %0, %1, %2, %0" : "+v"(d) : "v"(a), "v"(b));
}

__device__ __forceinline__ unsigned short f2bf(float f) {
  union { float f; unsigned u; } x; x.f = f;
  unsigned r = x.u + 0x7FFFu + ((x.u >> 16) & 1u);
  return (unsigned short)(r >> 16);
}
__device__ __forceinline__ float bf2f(unsigned short h) {
  union { unsigned u; float f; } x; x.u = ((unsigned)h) << 16;
  return x.f;
}

// sin/cos positional embedding, matches pos_ebb()
__device__ __forceinline__ float pe_val(int pos, int c) {
  int i = c >> 1;
  float freq = expf((float)(2 * i) * (-0.03597789207803197f)); // -ln(10000)/256
  float ang = (float)pos * freq;
  return (c & 1) ? cosf(ang) : sinf(ang);
}

// ---------------- conv stem: grouped conv1d(400->256, k=3, pad=1, g=4) + relu ----------------
__global__ __launch_bounds__(128) void k_convbase(const float* __restrict__ x,
                                                  const float* __restrict__ w,
                                                  const float* __restrict__ bias,
                                                  float* __restrict__ base) {
  int b = blockIdx.x >> 8, co = blockIdx.x & 255, t = threadIdx.x;
  if (t >= T99) return;
  int g = co >> 6;
  float acc = bias[co];
  const float* xp = x + (size_t)(b * FEAT + g * 100) * T99;
  const float* wp = w + (size_t)co * 300;
  for (int ic = 0; ic < 100; ++ic) {
    float x0 = (t > 0)  ? xp[ic * T99 + t - 1] : 0.f;
    float x1 = xp[ic * T99 + t];
    float x2 = (t < 98) ? xp[ic * T99 + t + 1] : 0.f;
    acc += wp[ic * 3] * x0 + wp[ic * 3 + 1] * x1 + wp[ic * 3 + 2] * x2;
  }
  base[(size_t)(b * CC + co) * T99 + t] = fmaxf(acc, 0.f);
}

// ---------------- build encoder inputs ----------------
// xg[t][b4][c], b4<2: base[b4,c,t]+pe(t,c); b4>=2: base[b4-2,c,98-t]+pe(t,c)
__global__ __launch_bounds__(256) void k_build_xg(const float* __restrict__ base, float* __restrict__ xg) {
  int idx = blockIdx.x * 256 + threadIdx.x;
  int t = idx >> 10, r = idx & 1023, b4 = r >> 8, c = r & 255;
  float v = (b4 < 2) ? base[(size_t)(b4 * CC + c) * T99 + t]
                     : base[(size_t)((b4 - 2) * CC + c) * T99 + (98 - t)];
  xg[idx] = v + pe_val(t, c);
}

// xl[ls][j=g*2+b][c] = base[b,c,ls*3+g] + pe33(ls,c)
__global__ __launch_bounds__(256) void k_build_xl(const float* __restrict__ base, float* __restrict__ xl) {
  int idx = blockIdx.x * 256 + threadIdx.x;
  int ls = idx / 1536, r = idx % 1536, j = r >> 8, c = r & 255;
  int g = j >> 1, b = j & 1, t = ls * 3 + g;
  xl[idx] = base[(size_t)(b * CC + c) * T99 + t] + pe_val(ls, c);
}

// ---------------- generic fp32 GEMM: Y[m,n] = act(sum_k A[m,k]*W[n,k] + bias[n] (+R[m,n])) ----------------
// flags: 1=relu, 2=residual
__global__ __launch_bounds__(256) void k_gemm(const float* __restrict__ A, const float* __restrict__ W,
                                              const float* __restrict__ bias, const float* __restrict__ R,
                                              float* __restrict__ Y, int M, int N, int K, int flags) {
  __shared__ float As[32][33], Ws[32][33];
  int tid = threadIdx.x, tx = tid & 15, ty = tid >> 4;
  int m0 = blockIdx.x * 32, n0 = blockIdx.y * 32;
  float a00 = 0, a01 = 0, a10 = 0, a11 = 0;
  for (int k0 = 0; k0 < K; k0 += 32) {
#pragma unroll
    for (int h = 0; h < 4; ++h) {
      int v = tid + h * 256, r = v >> 5, c = v & 31;
      As[r][c] = (m0 + r < M) ? A[(size_t)(m0 + r) * K + k0 + c] : 0.f;
      Ws[r][c] = W[(size_t)(n0 + r) * K + k0 + c];
    }
    __syncthreads();
#pragma unroll
    for (int kk = 0; kk < 32; ++kk) {
      float va0 = As[ty * 2][kk], va1 = As[ty * 2 + 1][kk];
      float w0 = Ws[tx * 2][kk], w1 = Ws[tx * 2 + 1][kk];
      a00 += va0 * w0; a01 += va0 * w1; a10 += va1 * w0; a11 += va1 * w1;
    }
    __syncthreads();
  }
  int m = m0 + ty * 2, n = n0 + tx * 2;
  float accs[2][2] = {{a00, a01}, {a10, a11}};
#pragma unroll
  for (int i = 0; i < 2; ++i) {
    if (m + i >= M) continue;
#pragma unroll
    for (int j = 0; j < 2; ++j) {
      float v = accs[i][j] + bias[n + j];
      if (flags & 2) v += R[(size_t)(m + i) * N + n + j];
      if (flags & 1) v = fmaxf(v, 0.f);
      Y[(size_t)(m + i) * N + n + j] = v;
    }
  }
}

// ---------------- attention: one block per (b,h,q) ----------------
__global__ __launch_bounds__(128) void k_attn(const float* __restrict__ qkv, float* __restrict__ att,
                                              int T_, int B_) {
  __shared__ float qv[32];
  __shared__ float red[128];
  __shared__ float pv[128];
  int tid = threadIdx.x;
  int q = blockIdx.x % T_;
  int h = (blockIdx.x / T_) % NHH;
  int b = blockIdx.x / (T_ * NHH);
  if (tid < 32) qv[tid] = qkv[(size_t)(q * B_ + b) * 768 + h * 32 + tid];
  __syncthreads();
  float s = -1e30f;
  if (tid < T_) {
    const float* kp = qkv + (size_t)(tid * B_ + b) * 768 + 256 + h * 32;
    float d = 0;
#pragma unroll
    for (int i = 0; i < 32; ++i) d += qv[i] * kp[i];
    s = d * 0.176776695296636881f; // 1/sqrt(32)
  }
  red[tid] = s; __syncthreads();
  for (int o = 64; o > 0; o >>= 1) { if (tid < o) red[tid] = fmaxf(red[tid], red[tid + o]); __syncthreads(); }
  float mx = red[0]; __syncthreads();
  float p = (tid < T_) ? expf(s - mx) : 0.f;
  pv[tid] = p; red[tid] = p; __syncthreads();
  for (int o = 64; o > 0; o >>= 1) { if (tid < o) red[tid] += red[tid + o]; __syncthreads(); }
  float denom = red[0];
  if (tid < 32) {
    float o = 0;
    for (int k = 0; k < T_; ++k) o += pv[k] * qkv[(size_t)(k * B_ + b) * 768 + 512 + h * 32 + tid];
    att[(size_t)(q * B_ + b) * 256 + h * 32 + tid] = o / denom;
  }
}

// ---------------- layer norm over C=256 ----------------
__global__ __launch_bounds__(256) void k_ln(const float* __restrict__ X, const float* __restrict__ g,
                                            const float* __restrict__ bb, float* __restrict__ Y) {
  __shared__ float rs[256], rq[256];
  int tok = blockIdx.x, c = threadIdx.x;
  float v = X[(size_t)tok * 256 + c];
  rs[c] = v; rq[c] = v * v; __syncthreads();
  for (int o = 128; o > 0; o >>= 1) { if (c < o) { rs[c] += rs[c + o]; rq[c] += rq[c + o]; } __syncthreads(); }
  float mu = rs[0] * (1.f / 256.f);
  float var = rq[0] * (1.f / 256.f) - mu * mu;
  Y[(size_t)tok * 256 + c] = (v - mu) * rsqrtf(var + 1e-5f) * g[c] + bb[c];
}

// ---------------- combine: base2 = local + f1 + flip(f2) ----------------
__global__ __launch_bounds__(256) void k_combine(const float* __restrict__ encl, const float* __restrict__ encg,
                                                 float* __restrict__ base2) {
  int idx = blockIdx.x * 256 + threadIdx.x;
  int t = idx % T99, c = (idx / T99) & 255, b = idx / (CC * T99);
  int ls = t / 3, g = t % 3;
  float v = encl[(size_t)(ls * 6 + g * 2 + b) * 256 + c]
          + encg[(size_t)(t * 4 + b) * 256 + c]
          + encg[(size_t)((98 - t) * 4 + 2 + b) * 256 + c];
  base2[idx] = v;
}

// ---------------- s-branch ----------------
__global__ __launch_bounds__(128) void k_s1(const float* __restrict__ base2, const float* __restrict__ w,
                                            const float* __restrict__ bias, float* __restrict__ sbuf) {
  int b = blockIdx.x >> 8, co = blockIdx.x & 255, t = threadIdx.x;
  if (t >= T99) return;
  int g = co >> 6;
  float acc = bias[co];
  const float* xp = base2 + (size_t)(b * CC + g * 64) * T99;
  const float* wp = w + (size_t)co * 192;
  for (int ic = 0; ic < 64; ++ic) {
    float x0 = (t > 0)  ? xp[ic * T99 + t - 1] : 0.f;
    float x1 = xp[ic * T99 + t];
    float x2 = (t < 98) ? xp[ic * T99 + t + 1] : 0.f;
    acc += wp[ic * 3] * x0 + wp[ic * 3 + 1] * x1 + wp[ic * 3 + 2] * x2;
  }
  sbuf[(size_t)(b * CC + co) * T99 + t] = fmaxf(acc, 0.f);
}

__global__ __launch_bounds__(256) void k_s2(const float* __restrict__ sbuf, const float* __restrict__ w,
                                            const float* __restrict__ bias, float* __restrict__ out) {
  int idx = threadIdx.x;
  if (idx >= 2 * T99) return;
  int b = idx / T99, t = idx % T99;
  float acc = bias[0];
  for (int c = 0; c < 256; ++c) acc += w[c] * sbuf[(size_t)(b * CC + c) * T99 + t];
  out[idx] = 1.f / (1.f + expf(-acc));
}

// ---------------- w3 transpose: w3t[n][ci][co] = c3_w[co][ci][n] ----------------
__global__ __launch_bounds__(256) void k_w3t(const float* __restrict__ c3w, float* __restrict__ w3t) {
  int idx = blockIdx.x * 256 + threadIdx.x;
  int co = idx & 255, ci = (idx >> 8) & 255, n = idx >> 16;
  w3t[idx] = c3w[((size_t)(co << 8) + ci) * 32 + n];
}

// ---------------- G[b][n][t][co] = sum_ci w3t[n][ci][co] * base2[b][ci][t] ----------------
__global__ __launch_bounds__(256) void k_G(const float* __restrict__ w3t, const float* __restrict__ base2,
                                           float* __restrict__ G) {
  int tc = blockIdx.x, n = blockIdx.y, b = blockIdx.z;
  int co = threadIdx.x;
  int t0 = tc * 25;
  float acc[25];
#pragma unroll
  for (int q = 0; q < 25; ++q) acc[q] = 0.f;
  const float* w = w3t + (size_t)n * 65536 + co;
  const float* bs = base2 + (size_t)b * CC * T99 + t0;
  for (int ci = 0; ci < 256; ++ci) {
    float wv = w[(size_t)ci * 256];
#pragma unroll
    for (int q = 0; q < 25; ++q) acc[q] += wv * bs[ci * T99 + q];  // t0+24 may read 1 past row: guarded at store
  }
#pragma unroll
  for (int q = 0; q < 25; ++q) {
    int t = t0 + q;
    if (t < T99) G[((size_t)(b * NS_ + n) * T99 + t) * 256 + co] = acc[q];
  }
}

// ---------------- p_pre: fused bm-gather + conv3d + relu -> bf16 channel-last ----------------
__global__ __launch_bounds__(256) void k_ppre(const float* __restrict__ G, const float* __restrict__ c3b,
                                              unsigned short* __restrict__ pinb) {
  __shared__ float ew[192];
  __shared__ int   et[192];
  __shared__ int   en[192];
  int e = blockIdx.x % T99, s = blockIdx.x / T99;
  int tid = threadIdx.x;
  if (s >= e) {
    unsigned short z = f2bf(fmaxf(c3b[tid], 0.f));
    pinb[((size_t)(0 * T99 + s) * T99 + e) * 256 + tid] = z;
    pinb[((size_t)(1 * T99 + s) * T99 + e) * 256 + tid] = z;
    return;
  }
  if (tid < 96) {
    double center = (double)(e - s + 1);
    double S = ((double)s - 0.5 * center) + ((2.0 * center - 1.0) / 95.0) * (double)tid;
    double dn = trunc(S);
    double dec = S - dn;
    int di = (int)dn;
    double uc = ceil(S);
    int ui = (int)uc;
    int n = tid / 3;
    bool vd = (dn >= 0.0) && (dn <= 98.0);
    bool vu = (uc >= 0.0) && (uc <= 98.0);
    ew[2 * tid]     = vd ? (float)((1.0 - dec) / 3.0) : 0.f;
    et[2 * tid]     = vd ? di : 0;
    en[2 * tid]     = n;
    ew[2 * tid + 1] = vu ? (float)(dec / 3.0) : 0.f;
    et[2 * tid + 1] = vu ? ui : 0;
    en[2 * tid + 1] = n;
  }
  __syncthreads();
  int co = tid;
  float a0 = 0.f, a1 = 0.f;
  const size_t bstride = (size_t)NS_ * T99 * 256;
  for (int k = 0; k < 192; ++k) {
    float w = ew[k];
    if (w != 0.f) {
      size_t off = ((size_t)en[k] * T99 + et[k]) * 256 + co;
      a0 += w * G[off];
      a1 += w * G[off + bstride];
    }
  }
  float bb = c3b[co];
  pinb[((size_t)(0 * T99 + s) * T99 + e) * 256 + co] = f2bf(fmaxf(a0 + bb, 0.f));
  pinb[((size_t)(1 * T99 + s) * T99 + e) * 256 + co] = f2bf(fmaxf(a1 + bb, 0.f));
}

// ---------------- weight transpose for conv: wb2[tap][co][ci] = pw[co][ci][tap] (bf16) ----------------
__global__ __launch_bounds__(256) void k_wb2(const float* __restrict__ pw, unsigned short* __restrict__ wb2) {
  int idx = blockIdx.x * 256 + threadIdx.x;
  int ci = idx & 255, co = (idx >> 8) & 255, tap = idx >> 16;
  wb2[idx] = f2bf(pw[((size_t)(co << 8) + ci) * 9 + tap]);
}

// ---------------- 3x3 conv (256->256, pad=1) as implicit GEMM, bf16 MFMA ----------------
// in/out: channel-last bf16 [b][i][j][c]; block tile: 128 spatial (16x8) x 128 co; 4 waves of 64x64
__global__ __launch_bounds__(256) void k_conv3x3(const unsigned short* __restrict__ in,
                                                 const unsigned short* __restrict__ wb2,
                                                 const float* __restrict__ bias,
                                                 unsigned short* __restrict__ out) {
  __shared__ __align__(16) unsigned short Al[128][40];
  __shared__ __align__(16) unsigned short Bl[128][40];
  int b = blockIdx.z;
  int co0 = blockIdx.y * 128;
  int ti = blockIdx.x / 13, tj = blockIdx.x % 13;
  int i0 = ti * 16, j0 = tj * 8;
  int tid = threadIdx.x;
  int lane = tid & 63, w = tid >> 6;
  int wm = w >> 1, wn = w & 1;

  f4v zero4 = {0.f, 0.f, 0.f, 0.f};
  f4v acc[4][4];
#pragma unroll
  for (int mt = 0; mt < 4; ++mt)
#pragma unroll
    for (int nt = 0; nt < 4; ++nt) acc[mt][nt] = zero4;

  for (int step = 0; step < 72; ++step) {
    int tap = step >> 3;
    int di = tap / 3 - 1, dj = tap % 3 - 1;
    int c0 = (step & 7) * 32;
#pragma unroll
    for (int h = 0; h < 2; ++h) {
      int v = tid + h * 256;
      int sp = v >> 2, kc = (v & 3) << 3;
      // A: input tile with halo shift
      int gi = i0 + (sp >> 3) + di;
      int gj = j0 + (sp & 7) + dj;
      s8v val = {0, 0, 0, 0, 0, 0, 0, 0};
      if (gi >= 0 && gi < T99 && gj >= 0 && gj < T99)
        val = *(const s8v*)&in[((size_t)(b * T99 + gi) * T99 + gj) * 256 + c0 + kc];
      *(s8v*)&Al[sp][kc] = val;
      // B: weights [tap][co][ci]
      *(s8v*)&Bl[sp][kc] = *(const s8v*)&wb2[((size_t)tap * 256 + (co0 + sp)) * 256 + c0 + kc];
    }
    __syncthreads();
    s8v af[4], bf[4];
#pragma unroll
    for (int mt = 0; mt < 4; ++mt)
      af[mt] = *(const s8v*)&Al[wm * 64 + mt * 16 + (lane & 15)][(lane >> 4) * 8];
#pragma unroll
    for (int nt = 0; nt < 4; ++nt)
      bf[nt] = *(const s8v*)&Bl[wn * 64 + nt * 16 + (lane & 15)][(lane >> 4) * 8];
#pragma unroll
    for (int mt = 0; mt < 4; ++mt)
#pragma unroll
      for (int nt = 0; nt < 4; ++nt) mfma_bf16(acc[mt][nt], af[mt], bf[nt]);
    __syncthreads();
  }
  // hazard guard before VALU reads of MFMA results
  asm volatile("s_nop 7\n\ts_nop 7\n\ts_nop 4");
#pragma unroll
  for (int mt = 0; mt < 4; ++mt) {
#pragma unroll
    for (int nt = 0; nt < 4; ++nt) {
      int coL = wn * 64 + nt * 16 + (lane & 15);
      int co = co0 + coL;
      float bv = bias[co];
#pragma unroll
      for (int r = 0; r < 4; ++r) {
        int sp = wm * 64 + mt * 16 + (lane >> 4) * 4 + r;
        int gi = i0 + (sp >> 3), gj = j0 + (sp & 7);
        if (gi < T99 && gj < T99) {
          float v = acc[mt][nt][r] + bv;
          v = fmaxf(v, 0.f);
          out[((size_t)(b * T99 + gi) * T99 + gj) * 256 + co] = f2bf(v);
        }
      }
    }
  }
}

// ---------------- p3 1x1 conv (256->2) + sigmoid -> cm ----------------
__global__ __launch_bounds__(256) void k_p3(const unsigned short* __restrict__ p2o,
                                            const float* __restrict__ w, const float* __restrict__ bias,
                                            float* __restrict__ cm) {
  int idx = blockIdx.x * 256 + threadIdx.x;
  if (idx >= 2 * 2 * T99 * T99) return;
  int j = idx % T99, i = (idx / T99) % T99, c2 = (idx / (T99 * T99)) % 2, b = idx / (2 * T99 * T99);
  float acc = bias[c2];
  const unsigned short* row = p2o + ((size_t)(b * T99 + i) * T99 + j) * 256;
  const float* wr = w + c2 * 256;
  for (int ci = 0; ci < 256; ++ci) acc += wr[ci] * bf2f(row[ci]);
  cm[idx] = 1.f / (1.f + expf(-acc));
}

// ---------------- host-side encoder driver ----------------
struct EncW {
  const float *qkvw, *qkvb, *ow, *ob, *l1w, *l1b, *l2w, *l2b, *n1g, *n1b, *n2g, *n2b, *nfg, *nfb;
};

static void run_encoder(float* x, int T_, int B_, int L, const EncW& W, float* out,
                        float* qkvb_, float* attb, float* yb, float* hb, hipStream_t st) {
  int ntok = T_ * B_;
  dim3 blk(256);
  for (int l = 0; l < L; ++l) {
    dim3 g1((ntok + 31) / 32, 768 / 32);
    k_gemm<<<g1, blk, 0, st>>>(x, W.qkvw + (size_t)l * 768 * 256, W.qkvb + l * 768, nullptr, qkvb_, ntok, 768, 256, 0);
    k_attn<<<dim3(B_ * NHH * T_), dim3(128), 0, st>>>(qkvb_, attb, T_, B_);
    dim3 g2((ntok + 31) / 32, 256 / 32);
    k_gemm<<<g2, blk, 0, st>>>(attb, W.ow + (size_t)l * 65536, W.ob + l * 256, x, yb, ntok, 256, 256, 2);
    k_ln<<<dim3(ntok), blk, 0, st>>>(yb, W.n1g + l * 256, W.n1b + l * 256, x);
    dim3 g3((ntok + 31) / 32, 1024 / 32);
    k_gemm<<<g3, blk, 0, st>>>(x, W.l1w + (size_t)l * 262144, W.l1b + l * 1024, nullptr, hb, ntok, 1024, 256, 1);
    k_gemm<<<g2, blk, 0, st>>>(hb, W.l2w + (size_t)l * 262144, W.l2b + l * 256, x, yb, ntok, 256, 1024, 2);
    k_ln<<<dim3(ntok), blk, 0, st>>>(yb, W.n2g + l * 256, W.n2b + l * 256, x);
  }
  k_ln<<<dim3(ntok), blk, 0, st>>>(x, W.nfg, W.nfb, out);
}

// ---------------- entry ----------------
extern "C" void kernel_launch(void* const* d_in, const int* in_sizes, int n_in,
                              void* d_out, int out_size, void* d_ws, size_t ws_size,
                              hipStream_t stream) {
  (void)in_sizes; (void)n_in; (void)out_size; (void)ws_size;
  const float* x    = (const float*)d_in[0];
  const float* cbw  = (const float*)d_in[1];
  const float* cbb  = (const float*)d_in[2];
  EncW tg = {(const float*)d_in[3],  (const float*)d_in[4],  (const float*)d_in[5],  (const float*)d_in[6],
             (const float*)d_in[7],  (const float*)d_in[8],  (const float*)d_in[9],  (const float*)d_in[10],
             (const float*)d_in[11], (const float*)d_in[12], (const float*)d_in[13], (const float*)d_in[14],
             (const float*)d_in[15], (const float*)d_in[16]};
  EncW tl = {(const float*)d_in[17], (const float*)d_in[18], (const float*)d_in[19], (const float*)d_in[20],
             (const float*)d_in[21], (const float*)d_in[22], (const float*)d_in[23], (const float*)d_in[24],
             (const float*)d_in[25], (const float*)d_in[26], (const float*)d_in[27], (const float*)d_in[28],
             (const float*)d_in[29], (const float*)d_in[30]};
  const float* s1w = (const float*)d_in[31];
  const float* s1b = (const float*)d_in[32];
  const float* s2w = (const float*)d_in[33];
  const float* s2b = (const float*)d_in[34];
  const float* c3w = (const float*)d_in[35];
  const float* c3b = (const float*)d_in[36];
  const float* p1w = (const float*)d_in[37];
  const float* p1b = (const float*)d_in[38];
  const float* p2w = (const float*)d_in[39];
  const float* p2b = (const float*)d_in[40];
  const float* p3w = (const float*)d_in[41];
  const float* p3b = (const float*)d_in[42];

  float* outp = (float*)d_out; // [cm 39204][start1 198]

  // workspace layout
  char* wp = (char*)d_ws;
  auto alloc = [&](size_t bytes) -> void* {
    void* p = (void*)wp;
    wp += (bytes + 255) & ~(size_t)255;
    return p;
  };
  float* base  = (float*)alloc(sizeof(float) * 2 * CC * T99);
  float* xg    = (float*)alloc(sizeof(float) * T99 * 4 * CC);
  float* xl    = (float*)alloc(sizeof(float) * LSTEP * 6 * CC);
  float* qkvb_ = (float*)alloc(sizeof(float) * 396 * 768);
  float* attb  = (float*)alloc(sizeof(float) * 396 * 256);
  float* yb    = (float*)alloc(sizeof(float) * 396 * 256);
  float* hb    = (float*)alloc(sizeof(float) * 396 * 1024);
  float* encg  = (float*)alloc(sizeof(float) * T99 * 4 * CC);
  float* encl  = (float*)alloc(sizeof(float) * LSTEP * 6 * CC);
  float* base2 = (float*)alloc(sizeof(float) * 2 * CC * T99);
  float* sbuf  = (float*)alloc(sizeof(float) * 2 * CC * T99);
  float* w3t   = (float*)alloc(sizeof(float) * 32 * 256 * 256);
  float* G     = (float*)alloc(sizeof(float) * 2 * NS_ * T99 * 256);
  unsigned short* pinb = (unsigned short*)alloc(sizeof(short) * 2 * T99 * T99 * 256);
  unsigned short* p1o  = (unsigned short*)alloc(sizeof(short) * 2 * T99 * T99 * 256);
  unsigned short* p2o  = (unsigned short*)alloc(sizeof(short) * 2 * T99 * T99 * 256);
  unsigned short* wb2  = (unsigned short*)alloc(sizeof(short) * 9 * 256 * 256);

  // 1. conv stem
  k_convbase<<<dim3(512), dim3(128), 0, stream>>>(x, cbw, cbb, base);
  // 2. local transformer
  k_build_xl<<<dim3(198), dim3(256), 0, stream>>>(base, xl);
  run_encoder(xl, LSTEP, 6, 3, tl, encl, qkvb_, attb, yb, hb, stream);
  // 3. global transformer (f1 & f2 batched, B'=4)
  k_build_xg<<<dim3(396), dim3(256), 0, stream>>>(base, xg);
  run_encoder(xg, T99, 4, 6, tg, encg, qkvb_, attb, yb, hb, stream);
  // 4. combine
  k_combine<<<dim3(198), dim3(256), 0, stream>>>(encl, encg, base2);
  // 5. s-branch -> start1
  k_s1<<<dim3(512), dim3(128), 0, stream>>>(base2, s1w, s1b, sbuf);
  k_s2<<<dim3(1), dim3(256), 0, stream>>>(sbuf, s2w, s2b, outp + 2 * 2 * T99 * T99);
  // 6. fused bm + conv3d
  k_w3t<<<dim3(8192), dim3(256), 0, stream>>>(c3w, w3t);
  k_G<<<dim3(4, 32, 2), dim3(256), 0, stream>>>(w3t, base2, G);
  k_ppre<<<dim3(T99 * T99), dim3(256), 0, stream>>>(G, c3b, pinb);
  // 7. p1 conv
  k_wb2<<<dim3(2304), dim3(256), 0, stream>>>(p1w, wb2);
  k_conv3x3<<<dim3(91, 2, 2), dim3(256), 0, stream>>>(pinb, wb2, p1b, p1o);
  // 8. p2 conv
  k_wb2<<<dim3(2304), dim3(256), 0, stream>>>(p2w, wb2);
  k_conv3x3<<<dim3(91, 2, 2), dim3(256), 0, stream>>>(p1o, wb2, p2b, p2o);
  // 9. p3 + sigmoid -> cm
  k_p3<<<dim3(154), dim3(256), 0, stream>>>(p2o, p3w, p3b, outp);
}

// Round 2
// 940.683 us; speedup vs baseline: 1.7615x; 1.7615x over previous
//
#include <hip/hip_runtime.h>
#include <math.h>

// ---------------- constants ----------------
#define T99   99
#define CC    256
#define NHH   8
#define FEAT  400
#define NS_   32
#define LSTEP 33

typedef __attribute__((ext_vector_type(8))) short s8v;   // 8 x bf16 (as raw u16)
typedef __attribute__((ext_vector_type(4))) float f4v;   // MFMA accumulator

__device__ __forceinline__ void mfma_bf16(f4v& d, s8v a, s8v b) {
  asm volatile("v_mfma_f32_16x16x32_bf16 %0, %1, %2, %0" : "+v"(d) : "v"(a), "v"(b));
}

__device__ __forceinline__ unsigned short f2bf(float f) {
  union { float f; unsigned u; } x; x.f = f;
  unsigned r = x.u + 0x7FFFu + ((x.u >> 16) & 1u);
  return (unsigned short)(r >> 16);
}
__device__ __forceinline__ float bf2f(unsigned short h) {
  union { unsigned u; float f; } x; x.u = ((unsigned)h) << 16;
  return x.f;
}

// sin/cos positional embedding, matches pos_ebb()
__device__ __forceinline__ float pe_val(int pos, int c) {
  int i = c >> 1;
  float freq = expf((float)(2 * i) * (-0.03597789207803197f)); // -ln(10000)/256
  float ang = (float)pos * freq;
  return (c & 1) ? cosf(ang) : sinf(ang);
}

// ---------------- conv stem: grouped conv1d(400->256, k=3, pad=1, g=4) + relu ----------------
__global__ __launch_bounds__(128) void k_convbase(const float* __restrict__ x,
                                                  const float* __restrict__ w,
                                                  const float* __restrict__ bias,
                                                  float* __restrict__ base) {
  int b = blockIdx.x >> 8, co = blockIdx.x & 255, t = threadIdx.x;
  if (t >= T99) return;
  int g = co >> 6;
  float acc = bias[co];
  const float* xp = x + (size_t)(b * FEAT + g * 100) * T99;
  const float* wp = w + (size_t)co * 300;
  for (int ic = 0; ic < 100; ++ic) {
    float x0 = (t > 0)  ? xp[ic * T99 + t - 1] : 0.f;
    float x1 = xp[ic * T99 + t];
    float x2 = (t < 98) ? xp[ic * T99 + t + 1] : 0.f;
    acc += wp[ic * 3] * x0 + wp[ic * 3 + 1] * x1 + wp[ic * 3 + 2] * x2;
  }
  base[(size_t)(b * CC + co) * T99 + t] = fmaxf(acc, 0.f);
}

// ---------------- weight conversion: pack {qkv,o,l1,l2} per layer into bf16 ----------------
// per-layer layout: qkv[196608] o[65536] l1[262144] l2[262144] = 786432
__global__ __launch_bounds__(256) void k_convW(const float* __restrict__ qkv, const float* __restrict__ o,
                                               const float* __restrict__ l1, const float* __restrict__ l2,
                                               int L, unsigned short* __restrict__ dst) {
  int total = L * 786432;
  for (int idx = blockIdx.x * 256 + threadIdx.x; idx < total; idx += gridDim.x * 256) {
    int l = idx / 786432, r = idx % 786432;
    float v;
    if (r < 196608)      v = qkv[(size_t)l * 196608 + r];
    else if (r < 262144) v = o[(size_t)l * 65536 + (r - 196608)];
    else if (r < 524288) v = l1[(size_t)l * 262144 + (r - 262144)];
    else                 v = l2[(size_t)l * 262144 + (r - 524288)];
    dst[idx] = f2bf(v);
  }
}

// ---------------- build encoder inputs (fp32 stream + bf16 mirror) ----------------
__global__ __launch_bounds__(256) void k_build_xg(const float* __restrict__ base, float* __restrict__ xg,
                                                  unsigned short* __restrict__ xgb) {
  int idx = blockIdx.x * 256 + threadIdx.x;
  int t = idx >> 10, r = idx & 1023, b4 = r >> 8, c = r & 255;
  float v = (b4 < 2) ? base[(size_t)(b4 * CC + c) * T99 + t]
                     : base[(size_t)((b4 - 2) * CC + c) * T99 + (98 - t)];
  v += pe_val(t, c);
  xg[idx] = v; xgb[idx] = f2bf(v);
}

__global__ __launch_bounds__(256) void k_build_xl(const float* __restrict__ base, float* __restrict__ xl,
                                                  unsigned short* __restrict__ xlb) {
  int idx = blockIdx.x * 256 + threadIdx.x;
  int ls = idx / 1536, r = idx % 1536, j = r >> 8, c = r & 255;
  int g = j >> 1, b = j & 1, t = ls * 3 + g;
  float v = base[(size_t)(b * CC + c) * T99 + t] + pe_val(ls, c);
  xl[idx] = v; xlb[idx] = f2bf(v);
}

// ---------------- bf16 MFMA GEMM: Y[m,n] = act(sum_k A[m,k]*W[n,k] + bias[n] (+R)) ----------------
// flags: 1=relu, 2=residual R, 4=write bf16 Yb, 8=skip fp32 Y
__global__ __launch_bounds__(256) void k_gemmb(const unsigned short* __restrict__ A,
                                               const unsigned short* __restrict__ W,
                                               const float* __restrict__ bias,
                                               const float* __restrict__ R,
                                               float* __restrict__ Y,
                                               unsigned short* __restrict__ Yb,
                                               int M, int N, int K, int flags) {
  __shared__ __align__(16) unsigned short Al[64][40];
  __shared__ __align__(16) unsigned short Bl[64][40];
  int tid = threadIdx.x;
  int m0 = blockIdx.x * 64, n0 = blockIdx.y * 64;
  int lane = tid & 63, w = tid >> 6, wm = w >> 1, wn = w & 1;
  int sp = tid >> 2, kc = (tid & 3) << 3;
  f4v zero4 = {0.f, 0.f, 0.f, 0.f};
  f4v acc[2][2];
#pragma unroll
  for (int mt = 0; mt < 2; ++mt)
#pragma unroll
    for (int nt = 0; nt < 2; ++nt) acc[mt][nt] = zero4;

  for (int k0 = 0; k0 < K; k0 += 32) {
    s8v av = {0, 0, 0, 0, 0, 0, 0, 0};
    int row = m0 + sp;
    if (row < M) av = *(const s8v*)&A[(size_t)row * K + k0 + kc];
    *(s8v*)&Al[sp][kc] = av;
    *(s8v*)&Bl[sp][kc] = *(const s8v*)&W[(size_t)(n0 + sp) * K + k0 + kc];
    __syncthreads();
    s8v af[2], bf[2];
#pragma unroll
    for (int mt = 0; mt < 2; ++mt)
      af[mt] = *(const s8v*)&Al[wm * 32 + mt * 16 + (lane & 15)][(lane >> 4) * 8];
#pragma unroll
    for (int nt = 0; nt < 2; ++nt)
      bf[nt] = *(const s8v*)&Bl[wn * 32 + nt * 16 + (lane & 15)][(lane >> 4) * 8];
#pragma unroll
    for (int mt = 0; mt < 2; ++mt)
#pragma unroll
      for (int nt = 0; nt < 2; ++nt) mfma_bf16(acc[mt][nt], af[mt], bf[nt]);
    __syncthreads();
  }
  asm volatile("s_nop 7\n\ts_nop 7\n\ts_nop 4");
#pragma unroll
  for (int mt = 0; mt < 2; ++mt) {
#pragma unroll
    for (int nt = 0; nt < 2; ++nt) {
      int col = n0 + wn * 32 + nt * 16 + (lane & 15);
      float bv = bias[col];
#pragma unroll
      for (int r = 0; r < 4; ++r) {
        int row = m0 + wm * 32 + mt * 16 + (lane >> 4) * 4 + r;
        if (row < M) {
          float v = acc[mt][nt][r] + bv;
          if (flags & 2) v += R[(size_t)row * N + col];
          if (flags & 1) v = fmaxf(v, 0.f);
          if (!(flags & 8)) Y[(size_t)row * N + col] = v;
          if (flags & 4) Yb[(size_t)row * N + col] = f2bf(v);
        }
      }
    }
  }
}

// ---------------- attention: one block per (b,h,q); fp32 math, bf16 output ----------------
__global__ __launch_bounds__(128) void k_attn(const float* __restrict__ qkv,
                                              unsigned short* __restrict__ attb,
                                              int T_, int B_) {
  __shared__ float qv[32];
  __shared__ float red[128];
  __shared__ float pv[128];
  int tid = threadIdx.x;
  int q = blockIdx.x % T_;
  int h = (blockIdx.x / T_) % NHH;
  int b = blockIdx.x / (T_ * NHH);
  if (tid < 32) qv[tid] = qkv[(size_t)(q * B_ + b) * 768 + h * 32 + tid];
  __syncthreads();
  float s = -1e30f;
  if (tid < T_) {
    const float* kp = qkv + (size_t)(tid * B_ + b) * 768 + 256 + h * 32;
    float d = 0;
#pragma unroll
    for (int i = 0; i < 32; ++i) d += qv[i] * kp[i];
    s = d * 0.176776695296636881f; // 1/sqrt(32)
  }
  red[tid] = s; __syncthreads();
  for (int o = 64; o > 0; o >>= 1) { if (tid < o) red[tid] = fmaxf(red[tid], red[tid + o]); __syncthreads(); }
  float mx = red[0]; __syncthreads();
  float p = (tid < T_) ? expf(s - mx) : 0.f;
  pv[tid] = p; red[tid] = p; __syncthreads();
  for (int o = 64; o > 0; o >>= 1) { if (tid < o) red[tid] += red[tid + o]; __syncthreads(); }
  float denom = red[0];
  if (tid < 32) {
    float o = 0;
    for (int k = 0; k < T_; ++k) o += pv[k] * qkv[(size_t)(k * B_ + b) * 768 + 512 + h * 32 + tid];
    attb[(size_t)(q * B_ + b) * 256 + h * 32 + tid] = f2bf(o / denom);
  }
}

// ---------------- layer norm over C=256; fp32 out + optional bf16 mirror ----------------
__global__ __launch_bounds__(256) void k_ln(const float* __restrict__ X, const float* __restrict__ g,
                                            const float* __restrict__ bb, float* __restrict__ Y,
                                            unsigned short* __restrict__ Yb) {
  __shared__ float rs[256], rq[256];
  int tok = blockIdx.x, c = threadIdx.x;
  float v = X[(size_t)tok * 256 + c];
  rs[c] = v; rq[c] = v * v; __syncthreads();
  for (int o = 128; o > 0; o >>= 1) { if (c < o) { rs[c] += rs[c + o]; rq[c] += rq[c + o]; } __syncthreads(); }
  float mu = rs[0] * (1.f / 256.f);
  float var = rq[0] * (1.f / 256.f) - mu * mu;
  float r = (v - mu) * rsqrtf(var + 1e-5f) * g[c] + bb[c];
  Y[(size_t)tok * 256 + c] = r;
  if (Yb) Yb[(size_t)tok * 256 + c] = f2bf(r);
}

// ---------------- combine: base2 = local + f1 + flip(f2) ----------------
__global__ __launch_bounds__(256) void k_combine(const float* __restrict__ encl, const float* __restrict__ encg,
                                                 float* __restrict__ base2) {
  int idx = blockIdx.x * 256 + threadIdx.x;
  int t = idx % T99, c = (idx / T99) & 255, b = idx / (CC * T99);
  int ls = t / 3, g = t % 3;
  float v = encl[(size_t)(ls * 6 + g * 2 + b) * 256 + c]
          + encg[(size_t)(t * 4 + b) * 256 + c]
          + encg[(size_t)((98 - t) * 4 + 2 + b) * 256 + c];
  base2[idx] = v;
}

// ---------------- s-branch ----------------
__global__ __launch_bounds__(128) void k_s1(const float* __restrict__ base2, const float* __restrict__ w,
                                            const float* __restrict__ bias, float* __restrict__ sbuf) {
  int b = blockIdx.x >> 8, co = blockIdx.x & 255, t = threadIdx.x;
  if (t >= T99) return;
  int g = co >> 6;
  float acc = bias[co];
  const float* xp = base2 + (size_t)(b * CC + g * 64) * T99;
  const float* wp = w + (size_t)co * 192;
  for (int ic = 0; ic < 64; ++ic) {
    float x0 = (t > 0)  ? xp[ic * T99 + t - 1] : 0.f;
    float x1 = xp[ic * T99 + t];
    float x2 = (t < 98) ? xp[ic * T99 + t + 1] : 0.f;
    acc += wp[ic * 3] * x0 + wp[ic * 3 + 1] * x1 + wp[ic * 3 + 2] * x2;
  }
  sbuf[(size_t)(b * CC + co) * T99 + t] = fmaxf(acc, 0.f);
}

// one block per (b,t): 256-thread reduction
__global__ __launch_bounds__(256) void k_s2(const float* __restrict__ sbuf, const float* __restrict__ w,
                                            const float* __restrict__ bias, float* __restrict__ out) {
  __shared__ float rs[256];
  int b = blockIdx.x / T99, t = blockIdx.x % T99, c = threadIdx.x;
  rs[c] = w[c] * sbuf[(size_t)(b * CC + c) * T99 + t];
  __syncthreads();
  for (int o = 128; o > 0; o >>= 1) { if (c < o) rs[c] += rs[c + o]; __syncthreads(); }
  if (c == 0) out[blockIdx.x] = 1.f / (1.f + expf(-(rs[0] + bias[0])));
}

// ---------------- w3 transpose: w3t[n][ci][co] = c3_w[co][ci][n] ----------------
__global__ __launch_bounds__(256) void k_w3t(const float* __restrict__ c3w, float* __restrict__ w3t) {
  int idx = blockIdx.x * 256 + threadIdx.x;
  int co = idx & 255, ci = (idx >> 8) & 255, n = idx >> 16;
  w3t[idx] = c3w[((size_t)(co << 8) + ci) * 32 + n];
}

// ---------------- Gb[n][t][co][b] (bf16) = sum_ci w3t[n][ci][co] * base2[b][ci][t] ----------------
__global__ __launch_bounds__(256) void k_G(const float* __restrict__ w3t, const float* __restrict__ base2,
                                           unsigned short* __restrict__ Gb) {
  int tc = blockIdx.x, n = blockIdx.y, b = blockIdx.z;
  int co = threadIdx.x;
  int t0 = tc * 25;
  float acc[25];
#pragma unroll
  for (int q = 0; q < 25; ++q) acc[q] = 0.f;
  const float* w = w3t + (size_t)n * 65536 + co;
  const float* bs = base2 + (size_t)b * CC * T99 + t0;
  for (int ci = 0; ci < 256; ++ci) {
    float wv = w[(size_t)ci * 256];
#pragma unroll
    for (int q = 0; q < 25; ++q) acc[q] += wv * bs[ci * T99 + q];
  }
#pragma unroll
  for (int q = 0; q < 25; ++q) {
    int t = t0 + q;
    if (t < T99) Gb[((size_t)(n * T99 + t) * 256 + co) * 2 + b] = f2bf(acc[q]);
  }
}

// ---------------- p_pre: fused bm-gather + conv3d + relu -> bf16 channel-last ----------------
// Gb is read as uint (b0|b1 bf16 pair) -> one load serves both batches
__global__ __launch_bounds__(256) void k_ppre(const unsigned int* __restrict__ Gb2,
                                              const float* __restrict__ c3b,
                                              unsigned short* __restrict__ pinb) {
  __shared__ float ew[192];
  __shared__ int   eoff[192];
  int e = blockIdx.x % T99, s = blockIdx.x / T99;
  int tid = threadIdx.x;
  if (s >= e) {
    unsigned short z = f2bf(fmaxf(c3b[tid], 0.f));
    pinb[((size_t)(0 * T99 + s) * T99 + e) * 256 + tid] = z;
    pinb[((size_t)(1 * T99 + s) * T99 + e) * 256 + tid] = z;
    return;
  }
  if (tid < 96) {
    double center = (double)(e - s + 1);
    double S = ((double)s - 0.5 * center) + ((2.0 * center - 1.0) / 95.0) * (double)tid;
    double dn = trunc(S);
    double dec = S - dn;
    int di = (int)dn;
    double uc = ceil(S);
    int ui = (int)uc;
    int n = tid / 3;
    bool vd = (dn >= 0.0) && (dn <= 98.0);
    bool vu = (uc >= 0.0) && (uc <= 98.0);
    ew[2 * tid]       = vd ? (float)((1.0 - dec) / 3.0) : 0.f;
    eoff[2 * tid]     = (n * T99 + (vd ? di : 0)) * 256;
    ew[2 * tid + 1]   = vu ? (float)(dec / 3.0) : 0.f;
    eoff[2 * tid + 1] = (n * T99 + (vu ? ui : 0)) * 256;
  }
  __syncthreads();
  int co = tid;
  float a0 = 0.f, a1 = 0.f;
  for (int k = 0; k < 192; ++k) {
    float w = ew[k];
    if (w != 0.f) {
      unsigned int pk = Gb2[(size_t)eoff[k] + co];
      a0 += w * bf2f((unsigned short)(pk & 0xFFFFu));
      a1 += w * bf2f((unsigned short)(pk >> 16));
    }
  }
  float bb = c3b[co];
  pinb[((size_t)(0 * T99 + s) * T99 + e) * 256 + co] = f2bf(fmaxf(a0 + bb, 0.f));
  pinb[((size_t)(1 * T99 + s) * T99 + e) * 256 + co] = f2bf(fmaxf(a1 + bb, 0.f));
}

// ---------------- weight transpose for conv: wb2[tap][co][ci] = pw[co][ci][tap] (bf16) ----------------
__global__ __launch_bounds__(256) void k_wb2(const float* __restrict__ pw, unsigned short* __restrict__ wb2) {
  int idx = blockIdx.x * 256 + threadIdx.x;
  int ci = idx & 255, co = (idx >> 8) & 255, tap = idx >> 16;
  wb2[idx] = f2bf(pw[((size_t)(co << 8) + ci) * 9 + tap]);
}

// ---------------- 3x3 conv (256->256, pad=1) as implicit GEMM, bf16 MFMA ----------------
__global__ __launch_bounds__(256) void k_conv3x3(const unsigned short* __restrict__ in,
                                                 const unsigned short* __restrict__ wb2,
                                                 const float* __restrict__ bias,
                                                 unsigned short* __restrict__ out) {
  __shared__ __align__(16) unsigned short Al[128][40];
  __shared__ __align__(16) unsigned short Bl[128][40];
  int b = blockIdx.z;
  int co0 = blockIdx.y * 128;
  int ti = blockIdx.x / 13, tj = blockIdx.x % 13;
  int i0 = ti * 16, j0 = tj * 8;
  int tid = threadIdx.x;
  int lane = tid & 63, w = tid >> 6;
  int wm = w >> 1, wn = w & 1;

  f4v zero4 = {0.f, 0.f, 0.f, 0.f};
  f4v acc[4][4];
#pragma unroll
  for (int mt = 0; mt < 4; ++mt)
#pragma unroll
    for (int nt = 0; nt < 4; ++nt) acc[mt][nt] = zero4;

  for (int step = 0; step < 72; ++step) {
    int tap = step >> 3;
    int di = tap / 3 - 1, dj = tap % 3 - 1;
    int c0 = (step & 7) * 32;
#pragma unroll
    for (int h = 0; h < 2; ++h) {
      int v = tid + h * 256;
      int sp = v >> 2, kc = (v & 3) << 3;
      int gi = i0 + (sp >> 3) + di;
      int gj = j0 + (sp & 7) + dj;
      s8v val = {0, 0, 0, 0, 0, 0, 0, 0};
      if (gi >= 0 && gi < T99 && gj >= 0 && gj < T99)
        val = *(const s8v*)&in[((size_t)(b * T99 + gi) * T99 + gj) * 256 + c0 + kc];
      *(s8v*)&Al[sp][kc] = val;
      *(s8v*)&Bl[sp][kc] = *(const s8v*)&wb2[((size_t)tap * 256 + (co0 + sp)) * 256 + c0 + kc];
    }
    __syncthreads();
    s8v af[4], bf[4];
#pragma unroll
    for (int mt = 0; mt < 4; ++mt)
      af[mt] = *(const s8v*)&Al[wm * 64 + mt * 16 + (lane & 15)][(lane >> 4) * 8];
#pragma unroll
    for (int nt = 0; nt < 4; ++nt)
      bf[nt] = *(const s8v*)&Bl[wn * 64 + nt * 16 + (lane & 15)][(lane >> 4) * 8];
#pragma unroll
    for (int mt = 0; mt < 4; ++mt)
#pragma unroll
      for (int nt = 0; nt < 4; ++nt) mfma_bf16(acc[mt][nt], af[mt], bf[nt]);
    __syncthreads();
  }
  asm volatile("s_nop 7\n\ts_nop 7\n\ts_nop 4");
#pragma unroll
  for (int mt = 0; mt < 4; ++mt) {
#pragma unroll
    for (int nt = 0; nt < 4; ++nt) {
      int coL = wn * 64 + nt * 16 + (lane & 15);
      int co = co0 + coL;
      float bv = bias[co];
#pragma unroll
      for (int r = 0; r < 4; ++r) {
        int sp = wm * 64 + mt * 16 + (lane >> 4) * 4 + r;
        int gi = i0 + (sp >> 3), gj = j0 + (sp & 7);
        if (gi < T99 && gj < T99) {
          float v = acc[mt][nt][r] + bv;
          v = fmaxf(v, 0.f);
          out[((size_t)(b * T99 + gi) * T99 + gj) * 256 + co] = f2bf(v);
        }
      }
    }
  }
}

// ---------------- p3 1x1 conv (256->2) + sigmoid -> cm ----------------
__global__ __launch_bounds__(256) void k_p3(const unsigned short* __restrict__ p2o,
                                            const float* __restrict__ w, const float* __restrict__ bias,
                                            float* __restrict__ cm) {
  int idx = blockIdx.x * 256 + threadIdx.x;
  if (idx >= 2 * 2 * T99 * T99) return;
  int j = idx % T99, i = (idx / T99) % T99, c2 = (idx / (T99 * T99)) % 2, b = idx / (2 * T99 * T99);
  float acc = bias[c2];
  const unsigned short* row = p2o + ((size_t)(b * T99 + i) * T99 + j) * 256;
  const float* wr = w + c2 * 256;
  for (int c8 = 0; c8 < 256; c8 += 8) {
    s8v v = *(const s8v*)&row[c8];
#pragma unroll
    for (int q = 0; q < 8; ++q) acc += wr[c8 + q] * bf2f((unsigned short)v[q]);
  }
  cm[idx] = 1.f / (1.f + expf(-acc));
}

// ---------------- host-side encoder driver ----------------
struct EncW {
  const float *qkvw, *qkvb, *ow, *ob, *l1w, *l1b, *l2w, *l2b, *n1g, *n1b, *n2g, *n2b, *nfg, *nfb;
};

static void run_encoder(float* x, unsigned short* xb, int T_, int B_, int L,
                        const EncW& W, const unsigned short* Wb, float* out,
                        float* qkvbuf, unsigned short* attb, float* yb, unsigned short* hbb,
                        hipStream_t st) {
  int ntok = T_ * B_;
  int mg = (ntok + 63) / 64;
  dim3 blk(256);
  for (int l = 0; l < L; ++l) {
    const unsigned short* wq  = Wb + (size_t)l * 786432;
    const unsigned short* wo  = wq + 196608;
    const unsigned short* wl1 = wq + 262144;
    const unsigned short* wl2 = wq + 524288;
    k_gemmb<<<dim3(mg, 12), blk, 0, st>>>(xb, wq, W.qkvb + l * 768, nullptr, qkvbuf, nullptr, ntok, 768, 256, 0);
    k_attn<<<dim3(B_ * NHH * T_), dim3(128), 0, st>>>(qkvbuf, attb, T_, B_);
    k_gemmb<<<dim3(mg, 4), blk, 0, st>>>(attb, wo, W.ob + l * 256, x, yb, nullptr, ntok, 256, 256, 2);
    k_ln<<<dim3(ntok), blk, 0, st>>>(yb, W.n1g + l * 256, W.n1b + l * 256, x, xb);
    k_gemmb<<<dim3(mg, 16), blk, 0, st>>>(xb, wl1, W.l1b + l * 1024, nullptr, nullptr, hbb, ntok, 1024, 256, 1 | 4 | 8);
    k_gemmb<<<dim3(mg, 4), blk, 0, st>>>(hbb, wl2, W.l2b + l * 256, x, yb, nullptr, ntok, 256, 1024, 2);
    k_ln<<<dim3(ntok), blk, 0, st>>>(yb, W.n2g + l * 256, W.n2b + l * 256, x, xb);
  }
  k_ln<<<dim3(ntok), blk, 0, st>>>(x, W.nfg, W.nfb, out, nullptr);
}

// ---------------- entry ----------------
extern "C" void kernel_launch(void* const* d_in, const int* in_sizes, int n_in,
                              void* d_out, int out_size, void* d_ws, size_t ws_size,
                              hipStream_t stream) {
  (void)in_sizes; (void)n_in; (void)out_size; (void)ws_size;
  const float* x    = (const float*)d_in[0];
  const float* cbw  = (const float*)d_in[1];
  const float* cbb  = (const float*)d_in[2];
  EncW tg = {(const float*)d_in[3],  (const float*)d_in[4],  (const float*)d_in[5],  (const float*)d_in[6],
             (const float*)d_in[7],  (const float*)d_in[8],  (const float*)d_in[9],  (const float*)d_in[10],
             (const float*)d_in[11], (const float*)d_in[12], (const float*)d_in[13], (const float*)d_in[14],
             (const float*)d_in[15], (const float*)d_in[16]};
  EncW tl = {(const float*)d_in[17], (const float*)d_in[18], (const float*)d_in[19], (const float*)d_in[20],
             (const float*)d_in[21], (const float*)d_in[22], (const float*)d_in[23], (const float*)d_in[24],
             (const float*)d_in[25], (const float*)d_in[26], (const float*)d_in[27], (const float*)d_in[28],
             (const float*)d_in[29], (const float*)d_in[30]};
  const float* s1w = (const float*)d_in[31];
  const float* s1b = (const float*)d_in[32];
  const float* s2w = (const float*)d_in[33];
  const float* s2b = (const float*)d_in[34];
  const float* c3w = (const float*)d_in[35];
  const float* c3b = (const float*)d_in[36];
  const float* p1w = (const float*)d_in[37];
  const float* p1b = (const float*)d_in[38];
  const float* p2w = (const float*)d_in[39];
  const float* p2b = (const float*)d_in[40];
  const float* p3w = (const float*)d_in[41];
  const float* p3b = (const float*)d_in[42];

  float* outp = (float*)d_out; // [cm 39204][start1 198]

  // workspace layout
  char* wp = (char*)d_ws;
  auto alloc = [&](size_t bytes) -> void* {
    void* p = (void*)wp;
    wp += (bytes + 255) & ~(size_t)255;
    return p;
  };
  float* base  = (float*)alloc(sizeof(float) * 2 * CC * T99);
  float* xg    = (float*)alloc(sizeof(float) * T99 * 4 * CC);
  float* xl    = (float*)alloc(sizeof(float) * LSTEP * 6 * CC);
  unsigned short* xgb = (unsigned short*)alloc(sizeof(short) * T99 * 4 * CC);
  unsigned short* xlb = (unsigned short*)alloc(sizeof(short) * LSTEP * 6 * CC);
  float* qkvbuf = (float*)alloc(sizeof(float) * 396 * 768);
  unsigned short* attb = (unsigned short*)alloc(sizeof(short) * 396 * 256);
  float* yb    = (float*)alloc(sizeof(float) * 396 * 256);
  unsigned short* hbb = (unsigned short*)alloc(sizeof(short) * 396 * 1024);
  float* encg  = (float*)alloc(sizeof(float) * T99 * 4 * CC);
  float* encl  = (float*)alloc(sizeof(float) * LSTEP * 6 * CC);
  float* base2 = (float*)alloc(sizeof(float) * 2 * CC * T99);
  float* sbuf  = (float*)alloc(sizeof(float) * 2 * CC * T99);
  float* w3t   = (float*)alloc(sizeof(float) * 32 * 256 * 256);
  unsigned short* Gb = (unsigned short*)alloc(sizeof(short) * 2 * NS_ * T99 * 256);
  unsigned short* pinb = (unsigned short*)alloc(sizeof(short) * 2 * T99 * T99 * 256);
  unsigned short* p1o  = (unsigned short*)alloc(sizeof(short) * 2 * T99 * T99 * 256);
  unsigned short* p2o  = (unsigned short*)alloc(sizeof(short) * 2 * T99 * T99 * 256);
  unsigned short* wb2  = (unsigned short*)alloc(sizeof(short) * 9 * 256 * 256);
  unsigned short* wtgb = (unsigned short*)alloc(sizeof(short) * 6 * 786432);
  unsigned short* wtlb = (unsigned short*)alloc(sizeof(short) * 3 * 786432);

  // 0. weight conversion (bf16)
  k_convW<<<dim3(4096), dim3(256), 0, stream>>>(tg.qkvw, tg.ow, tg.l1w, tg.l2w, 6, wtgb);
  k_convW<<<dim3(2048), dim3(256), 0, stream>>>(tl.qkvw, tl.ow, tl.l1w, tl.l2w, 3, wtlb);
  // 1. conv stem
  k_convbase<<<dim3(512), dim3(128), 0, stream>>>(x, cbw, cbb, base);
  // 2. local transformer
  k_build_xl<<<dim3(198), dim3(256), 0, stream>>>(base, xl, xlb);
  run_encoder(xl, xlb, LSTEP, 6, 3, tl, wtlb, encl, qkvbuf, attb, yb, hbb, stream);
  // 3. global transformer (f1 & f2 batched, B'=4)
  k_build_xg<<<dim3(396), dim3(256), 0, stream>>>(base, xg, xgb);
  run_encoder(xg, xgb, T99, 4, 6, tg, wtgb, encg, qkvbuf, attb, yb, hbb, stream);
  // 4. combine
  k_combine<<<dim3(198), dim3(256), 0, stream>>>(encl, encg, base2);
  // 5. s-branch -> start1
  k_s1<<<dim3(512), dim3(128), 0, stream>>>(base2, s1w, s1b, sbuf);
  k_s2<<<dim3(198), dim3(256), 0, stream>>>(sbuf, s2w, s2b, outp + 2 * 2 * T99 * T99);
  // 6. fused bm + conv3d
  k_w3t<<<dim3(8192), dim3(256), 0, stream>>>(c3w, w3t);
  k_G<<<dim3(4, 32, 2), dim3(256), 0, stream>>>(w3t, base2, Gb);
  k_ppre<<<dim3(T99 * T99), dim3(256), 0, stream>>>((const unsigned int*)Gb, c3b, pinb);
  // 7. p1 conv
  k_wb2<<<dim3(2304), dim3(256), 0, stream>>>(p1w, wb2);
  k_conv3x3<<<dim3(91, 2, 2), dim3(256), 0, stream>>>(pinb, wb2, p1b, p1o);
  // 8. p2 conv
  k_wb2<<<dim3(2304), dim3(256), 0, stream>>>(p2w, wb2);
  k_conv3x3<<<dim3(91, 2, 2), dim3(256), 0, stream>>>(p1o, wb2, p2b, p2o);
  // 9. p3 + sigmoid -> cm
  k_p3<<<dim3(154), dim3(256), 0, stream>>>(p2o, p3w, p3b, outp);
}